// Round 4
// baseline (86.677 us; speedup 1.0000x reference)
//
#include <hip/hip_runtime.h>

// LossUResidu: loss = mean_{b,vox} [ |A u - b| / mx_b * (1-f) ]
// = [ sum over img==0 voxels of |7pt clamped-neighbor laplacian(u)| ] / mx_b / (B*N).
// mx_b = max over voxels of dv(i)+dv(j)+dv(k) + (img!=0)*C, C = dx^2/eps_needle.
// gt never read. a1 = a2 = 1 (cubic grid).
// Single fused kernel: block partials -> ticket -> last block reduces + writes out.

namespace {
constexpr int NDIM  = 128;
constexpr int PL    = NDIM * NDIM;         // i-plane stride (floats)
constexpr int NPS   = NDIM * NDIM * NDIM;  // 2^21 voxels per sample
constexpr int BATCH = 4;
constexpr int BLOCKS_PER_S = 512;
constexpr int NBLOCKS = BATCH * BLOCKS_PER_S;  // 2048
constexpr int ITERS = 2;                   // i strided by 64 per thread
}

// One row-of-4 stencil: c center, xm/xp i-neighbors, ym/yp j-neighbors,
// lf/rg raw k-shuffles (clamped via klo/khi), g needle field.
__device__ __forceinline__ void stencil4(
        const float4& c, const float4& xm, const float4& xp,
        const float4& ym, const float4& yp, float lf_raw, float rg_raw,
        const float4& g, bool klo, bool khi, float dij, const float* dkt,
        float C, float& sum, float& mx) {
    float cc[4] = {c.x, c.y, c.z, c.w};
    float zl[4] = {klo ? c.x : lf_raw, c.x, c.y, c.z};
    float zr[4] = {c.y, c.z, c.w, khi ? c.w : rg_raw};
    float im[4] = {xm.x, xm.y, xm.z, xm.w};
    float ip[4] = {xp.x, xp.y, xp.z, xp.w};
    float jm[4] = {ym.x, ym.y, ym.z, ym.w};
    float jp[4] = {yp.x, yp.y, yp.z, yp.w};
    float gg[4] = {g.x, g.y, g.z, g.w};
#pragma unroll
    for (int t = 0; t < 4; ++t) {
        float lap = (im[t] + ip[t]) + (jm[t] + jp[t]) + (zl[t] + zr[t]) - 6.0f * cc[t];
        bool needle = (gg[t] != 0.0f);          // img is exactly -1/0/+1
        sum += needle ? 0.0f : fabsf(lap);      // |Au-b|: b==0, f_div_eps==0 here
        mx = fmaxf(mx, dij + dkt[t] + (needle ? C : 0.0f));
    }
}

__global__ __launch_bounds__(256) void loss_k(
        const float* __restrict__ u, const float* __restrict__ img,
        float* __restrict__ psum, float* __restrict__ pmax,
        int* __restrict__ cnt, float* __restrict__ out, float C) {
    int blk = blockIdx.x;
    int b   = blk >> 9;
    int q   = blk & (BLOCKS_PER_S - 1);
    int tid = q * 256 + threadIdx.x;     // [0, 131072) within sample
    int i0  = tid >> 11;                 // [0, 64)
    int j0  = (tid >> 5) & 63;           // j-pair index: rows 2j0, 2j0+1
    int kv  = tid & 31;
    int k4  = kv << 2;

    const float* ub = u   + (size_t)b * NPS;
    const float* gb = img + (size_t)b * NPS;
    int base0 = (i0 * NDIM + 2 * j0) * NDIM + k4;

    // per-thread invariants
    int ojm = (j0 == 0)  ? 0 : -NDIM;    // row A's j-1 (clamped)
    int ojp = (j0 == 63) ? 0 :  NDIM;    // row B's j+2 (clamped), rel. to B base
    float djA = (j0 == 0)  ? 1.0f : 2.0f;
    float djB = (j0 == 63) ? 1.0f : 2.0f;
    float dkt[4] = { (kv == 0) ? 1.0f : 2.0f, 2.0f, 2.0f,
                     (kv == 31) ? 1.0f : 2.0f };
    bool klo = (kv == 0), khi = (kv == 31);

    // ---- issue all loads up front (MLP); static indices only ----
    float4 cA[ITERS], cB[ITERS], ymA[ITERS], ypB[ITERS];
    float4 xmA[ITERS], xmB[ITERS], xpA[ITERS], xpB[ITERS], gA[ITERS], gB[ITERS];
#pragma unroll
    for (int s = 0; s < ITERS; ++s) {
        int base  = base0 + s * 64 * PL;
        int baseB = base + NDIM;
        int oim = (s == 0         && i0 == 0)  ? 0 : -PL;
        int oip = (s == ITERS - 1 && i0 == 63) ? 0 :  PL;
        cA[s]  = *(const float4*)(ub + base);
        cB[s]  = *(const float4*)(ub + baseB);
        ymA[s] = *(const float4*)(ub + base  + ojm);
        ypB[s] = *(const float4*)(ub + baseB + ojp);
        xmA[s] = *(const float4*)(ub + base  + oim);
        xmB[s] = *(const float4*)(ub + baseB + oim);
        xpA[s] = *(const float4*)(ub + base  + oip);
        xpB[s] = *(const float4*)(ub + baseB + oip);
        gA[s]  = *(const float4*)(gb + base);
        gB[s]  = *(const float4*)(gb + baseB);
    }

    float sum = 0.0f, mx = 0.0f;
#pragma unroll
    for (int s = 0; s < ITERS; ++s) {
        float di = 2.0f;
        if (s == 0         && i0 == 0)  di = 1.0f;
        if (s == ITERS - 1 && i0 == 63) di = 1.0f;
        // k-neighbors from lane shuffles (32-lane rows; edge lanes clamped)
        float lfA = __shfl_up(cA[s].w, 1), rgA = __shfl_down(cA[s].x, 1);
        float lfB = __shfl_up(cB[s].w, 1), rgB = __shfl_down(cB[s].x, 1);
        // row A: yp neighbor is row B (in regs); row B: ym neighbor is row A
        stencil4(cA[s], xmA[s], xpA[s], ymA[s], cB[s], lfA, rgA,
                 gA[s], klo, khi, di + djA, dkt, C, sum, mx);
        stencil4(cB[s], xmB[s], xpB[s], cA[s], ypB[s], lfB, rgB,
                 gB[s], klo, khi, di + djB, dkt, C, sum, mx);
    }

    // wave-64 tree reduce, then cross-wave via LDS
#pragma unroll
    for (int off = 32; off > 0; off >>= 1) {
        sum += __shfl_down(sum, off);
        mx = fmaxf(mx, __shfl_down(mx, off));
    }
    __shared__ float ssum[4], smax[4];
    __shared__ int lastflag;
    int wave = threadIdx.x >> 6, lane = threadIdx.x & 63;
    if (lane == 0) { ssum[wave] = sum; smax[wave] = mx; }
    __syncthreads();
    if (threadIdx.x == 0) {
        psum[blk] = (ssum[0] + ssum[1]) + (ssum[2] + ssum[3]);
        pmax[blk] = fmaxf(fmaxf(smax[0], smax[1]), fmaxf(smax[2], smax[3]));
        __threadfence();                              // release partials
        lastflag = (atomicAdd(cnt, 1) == NBLOCKS - 1);
    }
    __syncthreads();
    if (lastflag) {                                   // block-uniform
        __threadfence();                              // acquire partials
        double s = 0.0; float m = 0.0f;
        int base = wave * BLOCKS_PER_S;               // wave w -> sample w
#pragma unroll
        for (int r = 0; r < BLOCKS_PER_S / 64; ++r) {
            int idx = base + r * 64 + lane;
            s += (double)psum[idx];
            m = fmaxf(m, pmax[idx]);
        }
#pragma unroll
        for (int off = 32; off > 0; off >>= 1) {
            s += __shfl_down(s, off);
            m = fmaxf(m, __shfl_down(m, off));
        }
        __shared__ double wsum[4]; __shared__ float wmax[4];
        if (lane == 0) { wsum[wave] = s; wmax[wave] = m; }
        __syncthreads();
        if (threadIdx.x == 0) {
            double tot = 0.0;
            for (int bb = 0; bb < BATCH; ++bb) tot += wsum[bb] / (double)wmax[bb];
            out[0] = (float)(tot / ((double)BATCH * (double)NPS));  // WEIGHT_RESIDU == 1
        }
    }
}

extern "C" void kernel_launch(void* const* d_in, const int* in_sizes, int n_in,
                              void* d_out, int out_size, void* d_ws, size_t ws_size,
                              hipStream_t stream) {
    const float* u   = (const float*)d_in[0];  // "output" (field)
    // d_in[1] = "gt": shape-only, never read
    const float* img = (const float*)d_in[2];  // trinary field
    float* out = (float*)d_out;

    float* psum = (float*)d_ws;                        // 2048 floats
    float* pmax = psum + NBLOCKS;                      // 2048 floats
    int*   cnt  = (int*)((char*)d_ws + 2 * NBLOCKS * sizeof(float));

    const double dx = 2.0 / (NDIM - 1);
    const float  C  = (float)((dx * dx) / 1e-6);       // ~248.0005

    hipMemsetAsync(cnt, 0, sizeof(int), stream);       // ticket reset (graph-safe)
    hipLaunchKernelGGL(loss_k, dim3(NBLOCKS), dim3(256), 0, stream,
                       u, img, psum, pmax, cnt, out, C);
}

// Round 5
// 19.396 us; speedup vs baseline: 4.4689x; 4.4689x over previous
//
#include <hip/hip_runtime.h>

// LossUResidu: loss = mean_{b,vox} [ |A u - b| / mx_b * (1-f) ]
// = [ sum over img==0 voxels of |7pt clamped-neighbor laplacian(u)| ] / mx_b / (B*N).
// mx_b = max over voxels of dv(i)+dv(j)+dv(k) + (img!=0)*C, C = dx^2/eps_needle.
// gt never read. a1 = a2 = 1 (cubic grid).
// Two kernels (NO global atomics -- R4 showed a single-address ticket costs ~80us).
// Each thread: 2 j-rows x 4 consecutive i-planes x 4 k = 32 voxels, register
// streaming in i (center planes double as i-neighbors).

namespace {
constexpr int NDIM  = 128;
constexpr int PL    = NDIM * NDIM;         // i-plane stride (floats)
constexpr int NPS   = NDIM * NDIM * NDIM;  // 2^21 voxels per sample
constexpr int BATCH = 4;
constexpr int BLOCKS_PER_S = 256;
constexpr int NBLOCKS = BATCH * BLOCKS_PER_S;  // 1024
}

// One row-of-4 stencil (k via lane shuffles, clamped at kv edges).
__device__ __forceinline__ void stencil4(
        const float4& c, const float4& xm, const float4& xp,
        const float4& ym, const float4& yp, float lf_raw, float rg_raw,
        const float4& g, bool klo, bool khi, float dij, const float* dkt,
        float C, float& sum, float& mx) {
    float cc[4] = {c.x, c.y, c.z, c.w};
    float zl[4] = {klo ? c.x : lf_raw, c.x, c.y, c.z};
    float zr[4] = {c.y, c.z, c.w, khi ? c.w : rg_raw};
    float im[4] = {xm.x, xm.y, xm.z, xm.w};
    float ip[4] = {xp.x, xp.y, xp.z, xp.w};
    float jm[4] = {ym.x, ym.y, ym.z, ym.w};
    float jp[4] = {yp.x, yp.y, yp.z, yp.w};
    float gg[4] = {g.x, g.y, g.z, g.w};
#pragma unroll
    for (int t = 0; t < 4; ++t) {
        float lap = (im[t] + ip[t]) + (jm[t] + jp[t]) + (zl[t] + zr[t]) - 6.0f * cc[t];
        bool needle = (gg[t] != 0.0f);          // img is exactly -1/0/+1
        sum += needle ? 0.0f : fabsf(lap);      // |Au-b|: b==0, f_div_eps==0 here
        mx = fmaxf(mx, dij + dkt[t] + (needle ? C : 0.0f));
    }
}

__global__ __launch_bounds__(256) void loss_main_k(
        const float* __restrict__ u, const float* __restrict__ img,
        float* __restrict__ psum, float* __restrict__ pmax, float C) {
    int blk = blockIdx.x;
    int b   = blk >> 8;                      // / BLOCKS_PER_S
    int q   = blk & (BLOCKS_PER_S - 1);
    int tid = q * 256 + threadIdx.x;         // [0, 65536) within sample
    int i0  = tid >> 11;                     // [0, 32)  -> planes [4*i0, 4*i0+4)
    int j0  = (tid >> 5) & 63;               // rows 2*j0, 2*j0+1
    int kv  = tid & 31;
    int k4  = kv << 2;

    const float* ub = u   + (size_t)b * NPS;
    const float* gb = img + (size_t)b * NPS;
    int colA = (2 * j0) * NDIM + k4;         // in-plane offset, row A
    int pbase = 4 * i0;                      // first center plane

    // per-thread invariants
    int ojm = (j0 == 0)  ? 0 : -NDIM;
    int ojp = (j0 == 63) ? 0 :  NDIM;
    float djA = (j0 == 0)  ? 1.0f : 2.0f;
    float djB = (j0 == 63) ? 1.0f : 2.0f;
    float dkt[4] = { (kv == 0) ? 1.0f : 2.0f, 2.0f, 2.0f,
                     (kv == 31) ? 1.0f : 2.0f };
    bool klo = (kv == 0), khi = (kv == 31);

    // ---- plane window [4*i0-1 .. 4*i0+4] (6 planes, halos clamped) ----
    float4 cA[6], cB[6];
#pragma unroll
    for (int w = 0; w < 6; ++w) {
        int p = pbase - 1 + w;
        p = (p < 0) ? 0 : (p > NDIM - 1 ? NDIM - 1 : p);   // clamps only at w=0/5
        const float* pa = ub + p * PL + colA;
        cA[w] = *(const float4*)pa;
        cB[w] = *(const float4*)(pa + NDIM);
    }
    // j-halos + needle field for the 4 center planes
    float4 ymA[4], ypB[4], gA[4], gB[4];
#pragma unroll
    for (int s = 0; s < 4; ++s) {
        const float* pa = ub + (pbase + s) * PL + colA;
        ymA[s] = *(const float4*)(pa + ojm);
        ypB[s] = *(const float4*)(pa + NDIM + ojp);
        const float* pg = gb + (pbase + s) * PL + colA;
        gA[s] = *(const float4*)pg;
        gB[s] = *(const float4*)(pg + NDIM);
    }

    float sum = 0.0f, mx = 0.0f;
#pragma unroll
    for (int s = 0; s < 4; ++s) {
        float di = 2.0f;
        if (i0 == 0  && s == 0) di = 1.0f;
        if (i0 == 31 && s == 3) di = 1.0f;
        // k-neighbors across lanes (rows are 32-lane aligned)
        float lfA = __shfl_up(cA[s + 1].w, 1), rgA = __shfl_down(cA[s + 1].x, 1);
        float lfB = __shfl_up(cB[s + 1].w, 1), rgB = __shfl_down(cB[s + 1].x, 1);
        // row A: yp is row B (reg); row B: ym is row A (reg); i-nbrs from window
        stencil4(cA[s + 1], cA[s], cA[s + 2], ymA[s], cB[s + 1], lfA, rgA,
                 gA[s], klo, khi, di + djA, dkt, C, sum, mx);
        stencil4(cB[s + 1], cB[s], cB[s + 2], cA[s + 1], ypB[s], lfB, rgB,
                 gB[s], klo, khi, di + djB, dkt, C, sum, mx);
    }

    // wave-64 tree reduce, then cross-wave via LDS
#pragma unroll
    for (int off = 32; off > 0; off >>= 1) {
        sum += __shfl_down(sum, off);
        mx = fmaxf(mx, __shfl_down(mx, off));
    }
    __shared__ float ssum[4], smax[4];
    int wave = threadIdx.x >> 6, lane = threadIdx.x & 63;
    if (lane == 0) { ssum[wave] = sum; smax[wave] = mx; }
    __syncthreads();
    if (threadIdx.x == 0) {
        psum[blk] = (ssum[0] + ssum[1]) + (ssum[2] + ssum[3]);
        pmax[blk] = fmaxf(fmaxf(smax[0], smax[1]), fmaxf(smax[2], smax[3]));
    }
}

__global__ __launch_bounds__(256) void finalize_k(const float* __restrict__ psum,
                                                  const float* __restrict__ pmax,
                                                  float* __restrict__ out) {
    // one wave per sample; lane reads 4 partials (256/64)
    int wave = threadIdx.x >> 6, lane = threadIdx.x & 63;
    double s = 0.0; float m = 0.0f;
    int base = wave * BLOCKS_PER_S;
#pragma unroll
    for (int r = 0; r < BLOCKS_PER_S / 64; ++r) {
        int idx = base + r * 64 + lane;
        s += (double)psum[idx];
        m = fmaxf(m, pmax[idx]);
    }
#pragma unroll
    for (int off = 32; off > 0; off >>= 1) {
        s += __shfl_down(s, off);
        m = fmaxf(m, __shfl_down(m, off));
    }
    __shared__ double ws[4]; __shared__ float wm[4];
    if (lane == 0) { ws[wave] = s; wm[wave] = m; }
    __syncthreads();
    if (threadIdx.x == 0) {
        double tot = 0.0;
        for (int b = 0; b < BATCH; ++b) tot += ws[b] / (double)wm[b];
        out[0] = (float)(tot / ((double)BATCH * (double)NPS));  // WEIGHT_RESIDU == 1
    }
}

extern "C" void kernel_launch(void* const* d_in, const int* in_sizes, int n_in,
                              void* d_out, int out_size, void* d_ws, size_t ws_size,
                              hipStream_t stream) {
    const float* u   = (const float*)d_in[0];  // "output" (field)
    // d_in[1] = "gt": shape-only, never read
    const float* img = (const float*)d_in[2];  // trinary field
    float* out = (float*)d_out;

    float* psum = (float*)d_ws;                // 1024 floats
    float* pmax = psum + NBLOCKS;              // 1024 floats

    const double dx = 2.0 / (NDIM - 1);
    const float  C  = (float)((dx * dx) / 1e-6);  // ~248.0005

    hipLaunchKernelGGL(loss_main_k, dim3(NBLOCKS), dim3(256), 0, stream,
                       u, img, psum, pmax, C);
    hipLaunchKernelGGL(finalize_k, dim3(1), dim3(256), 0, stream, psum, pmax, out);
}

// Round 6
// 18.413 us; speedup vs baseline: 4.7073x; 1.0534x over previous
//
#include <hip/hip_runtime.h>

// LossUResidu: loss = mean_{b,vox} [ |A u - b| / mx_b * (1-f) ]
// = [ sum over img==0 voxels of |7pt clamped-neighbor laplacian(u)| ] / mx_b / (B*N).
// mx_b = max over voxels of dv(i)+dv(j)+dv(k) + (img!=0)*C, C = dx^2/eps_needle.
// gt never read. a1 = a2 = 1 (cubic grid). Two kernels, no global atomics.
// R6: occupancy-first. 8 vox/thread (j-pair x 4k), 4096 blocks, VGPR target <=64,
// all 10 float4 loads in flight -> 8 waves/SIMD, 32 waves/CU.

namespace {
constexpr int NDIM  = 128;
constexpr int PL    = NDIM * NDIM;         // i-plane stride (floats)
constexpr int NPS   = NDIM * NDIM * NDIM;  // 2^21 voxels per sample
constexpr int BATCH = 4;
constexpr int BLOCKS_PER_S = 1024;
constexpr int NBLOCKS = BATCH * BLOCKS_PER_S;  // 4096
}

// One row-of-4 stencil (k via lane shuffles, clamped at kv edges).
__device__ __forceinline__ void stencil4(
        const float4& c, const float4& xm, const float4& xp,
        const float4& ym, const float4& yp, float lf_raw, float rg_raw,
        const float4& g, bool klo, bool khi, float dij, const float* dkt,
        float C, float& sum, float& mx) {
    float cc[4] = {c.x, c.y, c.z, c.w};
    float zl[4] = {klo ? c.x : lf_raw, c.x, c.y, c.z};
    float zr[4] = {c.y, c.z, c.w, khi ? c.w : rg_raw};
    float im[4] = {xm.x, xm.y, xm.z, xm.w};
    float ip[4] = {xp.x, xp.y, xp.z, xp.w};
    float jm[4] = {ym.x, ym.y, ym.z, ym.w};
    float jp[4] = {yp.x, yp.y, yp.z, yp.w};
    float gg[4] = {g.x, g.y, g.z, g.w};
#pragma unroll
    for (int t = 0; t < 4; ++t) {
        float lap = (im[t] + ip[t]) + (jm[t] + jp[t]) + (zl[t] + zr[t]) - 6.0f * cc[t];
        bool needle = (gg[t] != 0.0f);          // img is exactly -1/0/+1
        sum += needle ? 0.0f : fabsf(lap);      // |Au-b|: b==0, f_div_eps==0 here
        mx = fmaxf(mx, dij + dkt[t] + (needle ? C : 0.0f));
    }
}

__global__ __launch_bounds__(256, 8) void loss_main_k(
        const float* __restrict__ u, const float* __restrict__ img,
        float* __restrict__ psum, float* __restrict__ pmax, float C) {
    int blk = blockIdx.x;
    int b   = blk >> 10;                     // / BLOCKS_PER_S
    int q   = blk & (BLOCKS_PER_S - 1);
    int t   = threadIdx.x;
    int i   = q >> 3;                        // plane [0,128); constant per block
    int j0  = (q & 7) * 8 + ((t >> 5) & 7);  // j-pair index [0,64): rows 2j0, 2j0+1
    int kv  = t & 31;
    int k4  = kv << 2;

    const float* ub = u   + (size_t)b * NPS;
    const float* gb = img + (size_t)b * NPS;
    int rowA = (i * NDIM + 2 * j0) * NDIM + k4;

    // invariants
    int ojm = (j0 == 0)  ? 0 : -NDIM;
    int ojp = (j0 == 63) ? 0 :  NDIM;
    int oim = (i == 0)          ? 0 : -PL;
    int oip = (i == NDIM - 1)   ? 0 :  PL;
    float di  = (i == 0 || i == NDIM - 1) ? 1.0f : 2.0f;
    float djA = (j0 == 0)  ? 1.0f : 2.0f;
    float djB = (j0 == 63) ? 1.0f : 2.0f;
    float dkt[4] = { (kv == 0) ? 1.0f : 2.0f, 2.0f, 2.0f,
                     (kv == 31) ? 1.0f : 2.0f };
    bool klo = (kv == 0), khi = (kv == 31);

    // ---- all 10 loads in flight ----
    const float* pa = ub + rowA;
    float4 cA  = *(const float4*)pa;
    float4 cB  = *(const float4*)(pa + NDIM);
    float4 ymA = *(const float4*)(pa + ojm);
    float4 ypB = *(const float4*)(pa + NDIM + ojp);
    float4 xmA = *(const float4*)(pa + oim);
    float4 xmB = *(const float4*)(pa + oim + NDIM);
    float4 xpA = *(const float4*)(pa + oip);
    float4 xpB = *(const float4*)(pa + oip + NDIM);
    const float* pg = gb + rowA;
    float4 gA  = *(const float4*)pg;
    float4 gB  = *(const float4*)(pg + NDIM);

    float sum = 0.0f, mx = 0.0f;
    // k-neighbors across lanes (rows are 32-lane aligned; edge lanes clamped)
    float lfA = __shfl_up(cA.w, 1), rgA = __shfl_down(cA.x, 1);
    float lfB = __shfl_up(cB.w, 1), rgB = __shfl_down(cB.x, 1);
    // row A: yp is row B (regs); row B: ym is row A (regs)
    stencil4(cA, xmA, xpA, ymA, cB, lfA, rgA, gA, klo, khi, di + djA, dkt, C, sum, mx);
    stencil4(cB, xmB, xpB, cA, ypB, lfB, rgB, gB, klo, khi, di + djB, dkt, C, sum, mx);

    // wave-64 tree reduce, then cross-wave via LDS
#pragma unroll
    for (int off = 32; off > 0; off >>= 1) {
        sum += __shfl_down(sum, off);
        mx = fmaxf(mx, __shfl_down(mx, off));
    }
    __shared__ float ssum[4], smax[4];
    int wave = threadIdx.x >> 6, lane = threadIdx.x & 63;
    if (lane == 0) { ssum[wave] = sum; smax[wave] = mx; }
    __syncthreads();
    if (threadIdx.x == 0) {
        psum[blk] = (ssum[0] + ssum[1]) + (ssum[2] + ssum[3]);
        pmax[blk] = fmaxf(fmaxf(smax[0], smax[1]), fmaxf(smax[2], smax[3]));
    }
}

__global__ __launch_bounds__(256) void finalize_k(const float* __restrict__ psum,
                                                  const float* __restrict__ pmax,
                                                  float* __restrict__ out) {
    // one wave per sample; lane reads 16 partials (1024/64)
    int wave = threadIdx.x >> 6, lane = threadIdx.x & 63;
    double s = 0.0; float m = 0.0f;
    int base = wave * BLOCKS_PER_S;
#pragma unroll
    for (int r = 0; r < BLOCKS_PER_S / 64; ++r) {
        int idx = base + r * 64 + lane;
        s += (double)psum[idx];
        m = fmaxf(m, pmax[idx]);
    }
#pragma unroll
    for (int off = 32; off > 0; off >>= 1) {
        s += __shfl_down(s, off);
        m = fmaxf(m, __shfl_down(m, off));
    }
    __shared__ double ws[4]; __shared__ float wm[4];
    if (lane == 0) { ws[wave] = s; wm[wave] = m; }
    __syncthreads();
    if (threadIdx.x == 0) {
        double tot = 0.0;
        for (int b = 0; b < BATCH; ++b) tot += ws[b] / (double)wm[b];
        out[0] = (float)(tot / ((double)BATCH * (double)NPS));  // WEIGHT_RESIDU == 1
    }
}

extern "C" void kernel_launch(void* const* d_in, const int* in_sizes, int n_in,
                              void* d_out, int out_size, void* d_ws, size_t ws_size,
                              hipStream_t stream) {
    const float* u   = (const float*)d_in[0];  // "output" (field)
    // d_in[1] = "gt": shape-only, never read
    const float* img = (const float*)d_in[2];  // trinary field
    float* out = (float*)d_out;

    float* psum = (float*)d_ws;                // 4096 floats
    float* pmax = psum + NBLOCKS;              // 4096 floats

    const double dx = 2.0 / (NDIM - 1);
    const float  C  = (float)((dx * dx) / 1e-6);  // ~248.0005

    hipLaunchKernelGGL(loss_main_k, dim3(NBLOCKS), dim3(256), 0, stream,
                       u, img, psum, pmax, C);
    hipLaunchKernelGGL(finalize_k, dim3(1), dim3(256), 0, stream, psum, pmax, out);
}

// Round 7
// 18.251 us; speedup vs baseline: 4.7492x; 1.0089x over previous
//
#include <hip/hip_runtime.h>

// LossUResidu: loss = mean_{b,vox} [ |A u - b| / mx_b * (1-f) ]
// = [ sum over img==0 voxels of |7pt clamped-neighbor laplacian(u)| ] / mx_b / (B*N).
// mx_b = max over voxels of dv(i)+dv(j)+dv(k) + (img!=0)*C, C = dx^2/eps_needle.
// gt never read. a1 = a2 = 1 (cubic grid). Two kernels, no global atomics.
// R7: i-pair streaming (16 vox/thread, centers double as i-halos, 2-phase loads
// to stay <=64 VGPR @ 8 waves/SIMD) + slim write-first block reduce.

namespace {
constexpr int NDIM  = 128;
constexpr int PL    = NDIM * NDIM;         // i-plane stride (floats)
constexpr int NPS   = NDIM * NDIM * NDIM;  // 2^21 voxels per sample
constexpr int BATCH = 4;
constexpr int BLOCKS_PER_S = 512;
constexpr int NBLOCKS = BATCH * BLOCKS_PER_S;  // 2048
}

// One row-of-4 stencil (k via lane shuffles, clamped at kv edges).
__device__ __forceinline__ void stencil4(
        const float4& c, const float4& xm, const float4& xp,
        const float4& ym, const float4& yp, float lf_raw, float rg_raw,
        const float4& g, bool klo, bool khi, float dij, const float* dkt,
        float C, float& sum, float& mx) {
    float cc[4] = {c.x, c.y, c.z, c.w};
    float zl[4] = {klo ? c.x : lf_raw, c.x, c.y, c.z};
    float zr[4] = {c.y, c.z, c.w, khi ? c.w : rg_raw};
    float im[4] = {xm.x, xm.y, xm.z, xm.w};
    float ip[4] = {xp.x, xp.y, xp.z, xp.w};
    float jm[4] = {ym.x, ym.y, ym.z, ym.w};
    float jp[4] = {yp.x, yp.y, yp.z, yp.w};
    float gg[4] = {g.x, g.y, g.z, g.w};
#pragma unroll
    for (int t = 0; t < 4; ++t) {
        float lap = (im[t] + ip[t]) + (jm[t] + jp[t]) + (zl[t] + zr[t]) - 6.0f * cc[t];
        bool needle = (gg[t] != 0.0f);          // img is exactly -1/0/+1
        sum += needle ? 0.0f : fabsf(lap);      // |Au-b|: b==0, f_div_eps==0 here
        mx = fmaxf(mx, dij + dkt[t] + (needle ? C : 0.0f));
    }
}

__global__ __launch_bounds__(256, 8) void loss_main_k(
        const float* __restrict__ u, const float* __restrict__ img,
        float* __restrict__ psum, float* __restrict__ pmax, float C) {
    int blk = blockIdx.x;
    int b   = blk >> 9;                      // / BLOCKS_PER_S
    int q   = blk & (BLOCKS_PER_S - 1);
    int t   = threadIdx.x;
    int i0  = q >> 3;                        // i-pair [0,64): planes 2i0, 2i0+1
    int j0  = (q & 7) * 8 + ((t >> 5) & 7);  // j-pair [0,64): rows 2j0, 2j0+1
    int kv  = t & 31;
    int k4  = kv << 2;
    int iA  = 2 * i0;                        // lower plane
    int iB  = iA + 1;                        // upper plane

    const float* ub = u   + (size_t)b * NPS;
    const float* gb = img + (size_t)b * NPS;
    int base0 = (iA * NDIM + 2 * j0) * NDIM + k4;   // plane A, row A
    int base1 = base0 + PL;                          // plane B, row A

    // invariants
    int ojm = (j0 == 0)  ? 0 : -NDIM;
    int ojp = (j0 == 63) ? 0 :  NDIM;
    int oim = (iA == 0)        ? 0 : -PL;    // plane A's i-1 (clamped)
    int oip = (iB == NDIM - 1) ? 0 :  PL;    // plane B's i+1 (clamped)
    float di0 = (iA == 0)        ? 1.0f : 2.0f;
    float di1 = (iB == NDIM - 1) ? 1.0f : 2.0f;
    float djA = (j0 == 0)  ? 1.0f : 2.0f;
    float djB = (j0 == 63) ? 1.0f : 2.0f;
    float dkt[4] = { (kv == 0) ? 1.0f : 2.0f, 2.0f, 2.0f,
                     (kv == 31) ? 1.0f : 2.0f };
    bool klo = (kv == 0), khi = (kv == 31);

    float sum = 0.0f, mx = 0.0f;

    // ---- phase 0: plane A (plane B centers double as A's xp) ----
    const float* p0 = ub + base0;
    const float* p1 = ub + base1;
    float4 c0A = *(const float4*)p0;
    float4 c0B = *(const float4*)(p0 + NDIM);
    float4 c1A = *(const float4*)p1;
    float4 c1B = *(const float4*)(p1 + NDIM);
    float4 xmA = *(const float4*)(p0 + oim);
    float4 xmB = *(const float4*)(p0 + oim + NDIM);
    float4 ym0 = *(const float4*)(p0 + ojm);
    float4 yp0 = *(const float4*)(p0 + NDIM + ojp);
    const float* g0 = gb + base0;
    float4 g0A = *(const float4*)g0;
    float4 g0B = *(const float4*)(g0 + NDIM);

    {
        float lfA = __shfl_up(c0A.w, 1), rgA = __shfl_down(c0A.x, 1);
        float lfB = __shfl_up(c0B.w, 1), rgB = __shfl_down(c0B.x, 1);
        stencil4(c0A, xmA, c1A, ym0, c0B, lfA, rgA, g0A, klo, khi,
                 di0 + djA, dkt, C, sum, mx);
        stencil4(c0B, xmB, c1B, c0A, yp0, lfB, rgB, g0B, klo, khi,
                 di0 + djB, dkt, C, sum, mx);
    }

    // ---- phase 1: plane B (plane A centers double as B's xm) ----
    float4 xpA = *(const float4*)(p1 + oip);
    float4 xpB = *(const float4*)(p1 + oip + NDIM);
    float4 ym1 = *(const float4*)(p1 + ojm);
    float4 yp1 = *(const float4*)(p1 + NDIM + ojp);
    const float* g1 = gb + base1;
    float4 g1A = *(const float4*)g1;
    float4 g1B = *(const float4*)(g1 + NDIM);

    {
        float lfA = __shfl_up(c1A.w, 1), rgA = __shfl_down(c1A.x, 1);
        float lfB = __shfl_up(c1B.w, 1), rgB = __shfl_down(c1B.x, 1);
        stencil4(c1A, c0A, xpA, ym1, c1B, lfA, rgA, g1A, klo, khi,
                 di1 + djA, dkt, C, sum, mx);
        stencil4(c1B, c0B, xpB, c1A, yp1, lfB, rgB, g1B, klo, khi,
                 di1 + djB, dkt, C, sum, mx);
    }

    // ---- slim write-first block reduce: 1 ds_write_b64/thread, wave0 tree ----
    __shared__ float2 red[256];
    red[t] = make_float2(sum, mx);
    __syncthreads();
    if (t < 64) {
        float2 a = red[t], b2 = red[t + 64], c2 = red[t + 128], d2 = red[t + 192];
        float s = (a.x + b2.x) + (c2.x + d2.x);
        float m = fmaxf(fmaxf(a.y, b2.y), fmaxf(c2.y, d2.y));
#pragma unroll
        for (int off = 32; off > 0; off >>= 1) {
            s += __shfl_down(s, off);
            m = fmaxf(m, __shfl_down(m, off));
        }
        if (t == 0) { psum[blk] = s; pmax[blk] = m; }
    }
}

__global__ __launch_bounds__(256) void finalize_k(const float* __restrict__ psum,
                                                  const float* __restrict__ pmax,
                                                  float* __restrict__ out) {
    // one wave per sample; lane reads 8 partials (512/64)
    int wave = threadIdx.x >> 6, lane = threadIdx.x & 63;
    double s = 0.0; float m = 0.0f;
    int base = wave * BLOCKS_PER_S;
#pragma unroll
    for (int r = 0; r < BLOCKS_PER_S / 64; ++r) {
        int idx = base + r * 64 + lane;
        s += (double)psum[idx];
        m = fmaxf(m, pmax[idx]);
    }
#pragma unroll
    for (int off = 32; off > 0; off >>= 1) {
        s += __shfl_down(s, off);
        m = fmaxf(m, __shfl_down(m, off));
    }
    __shared__ double ws[4]; __shared__ float wm[4];
    if (lane == 0) { ws[wave] = s; wm[wave] = m; }
    __syncthreads();
    if (threadIdx.x == 0) {
        double tot = 0.0;
        for (int b = 0; b < BATCH; ++b) tot += ws[b] / (double)wm[b];
        out[0] = (float)(tot / ((double)BATCH * (double)NPS));  // WEIGHT_RESIDU == 1
    }
}

extern "C" void kernel_launch(void* const* d_in, const int* in_sizes, int n_in,
                              void* d_out, int out_size, void* d_ws, size_t ws_size,
                              hipStream_t stream) {
    const float* u   = (const float*)d_in[0];  // "output" (field)
    // d_in[1] = "gt": shape-only, never read
    const float* img = (const float*)d_in[2];  // trinary field
    float* out = (float*)d_out;

    float* psum = (float*)d_ws;                // 2048 floats
    float* pmax = psum + NBLOCKS;              // 2048 floats

    const double dx = 2.0 / (NDIM - 1);
    const float  C  = (float)((dx * dx) / 1e-6);  // ~248.0005

    hipLaunchKernelGGL(loss_main_k, dim3(NBLOCKS), dim3(256), 0, stream,
                       u, img, psum, pmax, C);
    hipLaunchKernelGGL(finalize_k, dim3(1), dim3(256), 0, stream, psum, pmax, out);
}

// Round 8
// 17.755 us; speedup vs baseline: 4.8818x; 1.0279x over previous
//
#include <hip/hip_runtime.h>

// LossUResidu: loss = mean_{b,vox} [ |A u - b| / mx_b * (1-f) ]
// = [ sum over img==0 voxels of |7pt clamped-neighbor laplacian(u)| ] / mx_b / (B*N).
// mx_b = max over voxels of dv(i)+dv(j)+dv(k) + (img!=0)*C, C = dx^2/eps_needle.
// gt never read. a1 = a2 = 1 (cubic grid). Two kernels, no global atomics.
// R8 = R7 + XCD-chunked bijective blockIdx swizzle (T1): each XCD gets a
// contiguous half-sample slab (~8.4 MB) instead of the whole 67 MB scattered.

namespace {
constexpr int NDIM  = 128;
constexpr int PL    = NDIM * NDIM;         // i-plane stride (floats)
constexpr int NPS   = NDIM * NDIM * NDIM;  // 2^21 voxels per sample
constexpr int BATCH = 4;
constexpr int BLOCKS_PER_S = 512;
constexpr int NBLOCKS = BATCH * BLOCKS_PER_S;  // 2048 (divisible by 8 XCDs)
constexpr int NXCD = 8;
}

// One row-of-4 stencil (k via lane shuffles, clamped at kv edges).
__device__ __forceinline__ void stencil4(
        const float4& c, const float4& xm, const float4& xp,
        const float4& ym, const float4& yp, float lf_raw, float rg_raw,
        const float4& g, bool klo, bool khi, float dij, const float* dkt,
        float C, float& sum, float& mx) {
    float cc[4] = {c.x, c.y, c.z, c.w};
    float zl[4] = {klo ? c.x : lf_raw, c.x, c.y, c.z};
    float zr[4] = {c.y, c.z, c.w, khi ? c.w : rg_raw};
    float im[4] = {xm.x, xm.y, xm.z, xm.w};
    float ip[4] = {xp.x, xp.y, xp.z, xp.w};
    float jm[4] = {ym.x, ym.y, ym.z, ym.w};
    float jp[4] = {yp.x, yp.y, yp.z, yp.w};
    float gg[4] = {g.x, g.y, g.z, g.w};
#pragma unroll
    for (int t = 0; t < 4; ++t) {
        float lap = (im[t] + ip[t]) + (jm[t] + jp[t]) + (zl[t] + zr[t]) - 6.0f * cc[t];
        bool needle = (gg[t] != 0.0f);          // img is exactly -1/0/+1
        sum += needle ? 0.0f : fabsf(lap);      // |Au-b|: b==0, f_div_eps==0 here
        mx = fmaxf(mx, dij + dkt[t] + (needle ? C : 0.0f));
    }
}

__global__ __launch_bounds__(256, 8) void loss_main_k(
        const float* __restrict__ u, const float* __restrict__ img,
        float* __restrict__ psum, float* __restrict__ pmax, float C) {
    // XCD-chunked swizzle: HW round-robins blockIdx%8 across XCDs; remap so
    // XCD x owns contiguous work indices [x*256, (x+1)*256) (bijective).
    int blk = blockIdx.x;
    int w   = (blk & (NXCD - 1)) * (NBLOCKS / NXCD) + (blk >> 3);

    int b   = w >> 9;                        // / BLOCKS_PER_S
    int q   = w & (BLOCKS_PER_S - 1);
    int t   = threadIdx.x;
    int i0  = q >> 3;                        // i-pair [0,64): planes 2i0, 2i0+1
    int j0  = (q & 7) * 8 + ((t >> 5) & 7);  // j-pair [0,64): rows 2j0, 2j0+1
    int kv  = t & 31;
    int k4  = kv << 2;
    int iA  = 2 * i0;                        // lower plane
    int iB  = iA + 1;                        // upper plane

    const float* ub = u   + (size_t)b * NPS;
    const float* gb = img + (size_t)b * NPS;
    int base0 = (iA * NDIM + 2 * j0) * NDIM + k4;   // plane A, row A
    int base1 = base0 + PL;                          // plane B, row A

    // invariants
    int ojm = (j0 == 0)  ? 0 : -NDIM;
    int ojp = (j0 == 63) ? 0 :  NDIM;
    int oim = (iA == 0)        ? 0 : -PL;    // plane A's i-1 (clamped)
    int oip = (iB == NDIM - 1) ? 0 :  PL;    // plane B's i+1 (clamped)
    float di0 = (iA == 0)        ? 1.0f : 2.0f;
    float di1 = (iB == NDIM - 1) ? 1.0f : 2.0f;
    float djA = (j0 == 0)  ? 1.0f : 2.0f;
    float djB = (j0 == 63) ? 1.0f : 2.0f;
    float dkt[4] = { (kv == 0) ? 1.0f : 2.0f, 2.0f, 2.0f,
                     (kv == 31) ? 1.0f : 2.0f };
    bool klo = (kv == 0), khi = (kv == 31);

    float sum = 0.0f, mx = 0.0f;

    // ---- phase 0: plane A (plane B centers double as A's xp) ----
    const float* p0 = ub + base0;
    const float* p1 = ub + base1;
    float4 c0A = *(const float4*)p0;
    float4 c0B = *(const float4*)(p0 + NDIM);
    float4 c1A = *(const float4*)p1;
    float4 c1B = *(const float4*)(p1 + NDIM);
    float4 xmA = *(const float4*)(p0 + oim);
    float4 xmB = *(const float4*)(p0 + oim + NDIM);
    float4 ym0 = *(const float4*)(p0 + ojm);
    float4 yp0 = *(const float4*)(p0 + NDIM + ojp);
    const float* g0 = gb + base0;
    float4 g0A = *(const float4*)g0;
    float4 g0B = *(const float4*)(g0 + NDIM);

    {
        float lfA = __shfl_up(c0A.w, 1), rgA = __shfl_down(c0A.x, 1);
        float lfB = __shfl_up(c0B.w, 1), rgB = __shfl_down(c0B.x, 1);
        stencil4(c0A, xmA, c1A, ym0, c0B, lfA, rgA, g0A, klo, khi,
                 di0 + djA, dkt, C, sum, mx);
        stencil4(c0B, xmB, c1B, c0A, yp0, lfB, rgB, g0B, klo, khi,
                 di0 + djB, dkt, C, sum, mx);
    }

    // ---- phase 1: plane B (plane A centers double as B's xm) ----
    float4 xpA = *(const float4*)(p1 + oip);
    float4 xpB = *(const float4*)(p1 + oip + NDIM);
    float4 ym1 = *(const float4*)(p1 + ojm);
    float4 yp1 = *(const float4*)(p1 + NDIM + ojp);
    const float* g1 = gb + base1;
    float4 g1A = *(const float4*)g1;
    float4 g1B = *(const float4*)(g1 + NDIM);

    {
        float lfA = __shfl_up(c1A.w, 1), rgA = __shfl_down(c1A.x, 1);
        float lfB = __shfl_up(c1B.w, 1), rgB = __shfl_down(c1B.x, 1);
        stencil4(c1A, c0A, xpA, ym1, c1B, lfA, rgA, g1A, klo, khi,
                 di1 + djA, dkt, C, sum, mx);
        stencil4(c1B, c0B, xpB, c1A, yp1, lfB, rgB, g1B, klo, khi,
                 di1 + djB, dkt, C, sum, mx);
    }

    // ---- slim write-first block reduce: 1 ds_write_b64/thread, wave0 tree ----
    __shared__ float2 red[256];
    red[t] = make_float2(sum, mx);
    __syncthreads();
    if (t < 64) {
        float2 a = red[t], b2 = red[t + 64], c2 = red[t + 128], d2 = red[t + 192];
        float s = (a.x + b2.x) + (c2.x + d2.x);
        float m = fmaxf(fmaxf(a.y, b2.y), fmaxf(c2.y, d2.y));
#pragma unroll
        for (int off = 32; off > 0; off >>= 1) {
            s += __shfl_down(s, off);
            m = fmaxf(m, __shfl_down(m, off));
        }
        if (t == 0) { psum[w] = s; pmax[w] = m; }   // bijective -> no clash
    }
}

__global__ __launch_bounds__(256) void finalize_k(const float* __restrict__ psum,
                                                  const float* __restrict__ pmax,
                                                  float* __restrict__ out) {
    // one wave per sample; lane reads 8 partials (512/64)
    int wave = threadIdx.x >> 6, lane = threadIdx.x & 63;
    double s = 0.0; float m = 0.0f;
    int base = wave * BLOCKS_PER_S;
#pragma unroll
    for (int r = 0; r < BLOCKS_PER_S / 64; ++r) {
        int idx = base + r * 64 + lane;
        s += (double)psum[idx];
        m = fmaxf(m, pmax[idx]);
    }
#pragma unroll
    for (int off = 32; off > 0; off >>= 1) {
        s += __shfl_down(s, off);
        m = fmaxf(m, __shfl_down(m, off));
    }
    __shared__ double ws[4]; __shared__ float wm[4];
    if (lane == 0) { ws[wave] = s; wm[wave] = m; }
    __syncthreads();
    if (threadIdx.x == 0) {
        double tot = 0.0;
        for (int b = 0; b < BATCH; ++b) tot += ws[b] / (double)wm[b];
        out[0] = (float)(tot / ((double)BATCH * (double)NPS));  // WEIGHT_RESIDU == 1
    }
}

extern "C" void kernel_launch(void* const* d_in, const int* in_sizes, int n_in,
                              void* d_out, int out_size, void* d_ws, size_t ws_size,
                              hipStream_t stream) {
    const float* u   = (const float*)d_in[0];  // "output" (field)
    // d_in[1] = "gt": shape-only, never read
    const float* img = (const float*)d_in[2];  // trinary field
    float* out = (float*)d_out;

    float* psum = (float*)d_ws;                // 2048 floats
    float* pmax = psum + NBLOCKS;              // 2048 floats

    const double dx = 2.0 / (NDIM - 1);
    const float  C  = (float)((dx * dx) / 1e-6);  // ~248.0005

    hipLaunchKernelGGL(loss_main_k, dim3(NBLOCKS), dim3(256), 0, stream,
                       u, img, psum, pmax, C);
    hipLaunchKernelGGL(finalize_k, dim3(1), dim3(256), 0, stream, psum, pmax, out);
}